// Round 2
// baseline (2581.878 us; speedup 1.0000x reference)
//
#include <hip/hip_runtime.h>

// Problem constants (from reference): B=4, L=64, C=64, H=32, W=32, K=3, CONN=4
#define NIMG 256          // B*L
#define CCH 64
#define HH 32
#define WW 32
#define HWSZ 1024         // 32*32
#define IMGSZ 65536       // CCH*HWSZ floats per image
#define KTAPS 9
#define KROW 576          // CCH*KTAPS

// ---------------------------------------------------------------------------
// Build neighbor index list nbr[n][4] from the adjacency mask.
// Handles both possible stagings of the bool mask (1-byte bool or int32):
// count nonzero bytes in the first 16384 bytes -> 1024 if byte-bool (exactly
// CONN per row over all B*L rows), 256 if int32 (first quarter = b=0 only).
// ---------------------------------------------------------------------------
__global__ __launch_bounds__(256) void build_nbr_kernel(const unsigned char* __restrict__ mraw,
                                                        int* __restrict__ nbr) {
    __shared__ int nz;
    int t = threadIdx.x;
    if (t == 0) nz = 0;
    __syncthreads();
    int local = 0;
    for (int i = t; i < 16384; i += 256) local += (mraw[i] != 0) ? 1 : 0;
    atomicAdd(&nz, local);
    __syncthreads();
    bool isByte = (nz == 1024);
    const int* mi = (const int*)mraw;
    int c = 0;
    int base = t * 64;   // row t = (b*64 + i), 64 columns
    for (int j = 0; j < 64; ++j) {
        int v = isByte ? (int)mraw[base + j] : mi[base + j];
        if (v != 0 && c < 4) { nbr[t * 4 + c] = j; ++c; }
    }
    for (; c < 4; ++c) nbr[t * 4 + c] = -1;
}

// ---------------------------------------------------------------------------
// Direct 3x3 conv, stride 1, pad 1, NCHW, C=64->64, f32.
// Block: 256 threads covers one image x one 8-row stripe x 16 output chans.
// Thread: 4 consecutive x-pixels x 4 output chans.
// Weights for the block's 16 co staged in LDS laid out [ci*9+tap][16co] so the
// inner loop reads one aligned float4 per (ci,tap).
// grid = 256 images * 4 stripes * 4 co-groups = 4096 blocks.
// ---------------------------------------------------------------------------
__global__ __launch_bounds__(256) void conv3x3_kernel(const float* __restrict__ in,
                                                      const float* __restrict__ w,
                                                      const float* __restrict__ bias,
                                                      float* __restrict__ out) {
    __shared__ float wlds[KROW * 16];   // [r=ci*9+tap][co_local] : 36 KiB
    int bid = blockIdx.x;
    int n      = bid >> 4;
    int stripe = bid & 3;
    int cog    = (bid >> 2) & 3;
    int cobase = cog * 16;
    int t = threadIdx.x;

    // stage weights: wlds[r*16 + col] = w[(cobase+col)*576 + r]
    for (int idx = t; idx < KROW * 16; idx += 256) {
        int col = idx & 15;
        int r   = idx >> 4;
        wlds[idx] = w[(cobase + col) * KROW + r];
    }
    __syncthreads();

    int pg  = t & 63;            // pixel-group 0..63
    int cq  = t >> 6;            // co quad 0..3
    int row = stripe * 8 + (pg >> 3);
    int xb  = (pg & 7) * 4;

    float acc[4][4];             // [cc][px]
    #pragma unroll
    for (int cc = 0; cc < 4; ++cc) {
        float bv = bias[cobase + cq * 4 + cc];
        #pragma unroll
        for (int px = 0; px < 4; ++px) acc[cc][px] = bv;
    }

    const float* inimg = in + n * IMGSZ;
    for (int ci = 0; ci < CCH; ++ci) {
        const float* inch = inimg + ci * HWSZ;
        #pragma unroll
        for (int dy = 0; dy < 3; ++dy) {
            int y = row + dy - 1;
            float v0, v1, v2, v3, v4, v5;
            if (y >= 0 && y < HH) {
                const float* rp = inch + y * WW + xb;
                float4 mid = *(const float4*)rp;
                v1 = mid.x; v2 = mid.y; v3 = mid.z; v4 = mid.w;
                v0 = (xb > 0)  ? rp[-1] : 0.f;
                v5 = (xb < 28) ? rp[4]  : 0.f;
            } else {
                v0 = v1 = v2 = v3 = v4 = v5 = 0.f;
            }
            float vv[6] = {v0, v1, v2, v3, v4, v5};
            #pragma unroll
            for (int dx = 0; dx < 3; ++dx) {
                // weights for 4 cc at this (ci, dy, dx): one aligned float4
                float4 wv = *(const float4*)&wlds[(ci * KTAPS + dy * 3 + dx) * 16 + cq * 4];
                float wc[4] = {wv.x, wv.y, wv.z, wv.w};
                #pragma unroll
                for (int px = 0; px < 4; ++px) {
                    float xv = vv[px + dx];
                    #pragma unroll
                    for (int cc = 0; cc < 4; ++cc)
                        acc[cc][px] = fmaf(wc[cc], xv, acc[cc][px]);
                }
            }
        }
    }

    #pragma unroll
    for (int cc = 0; cc < 4; ++cc) {
        int co = cobase + cq * 4 + cc;
        float4 o = make_float4(acc[cc][0], acc[cc][1], acc[cc][2], acc[cc][3]);
        *(float4*)(out + ((n * CCH + co) * HH + row) * WW + xb) = o;
    }
}

// ---------------------------------------------------------------------------
// h = relu(hx + sum_k nset[neighbor_k])   (in-place on hx), float4-vectorized
// ---------------------------------------------------------------------------
__global__ __launch_bounds__(256) void agg_relu_kernel(float* __restrict__ hx,
                                                       const float* __restrict__ nset,
                                                       const int* __restrict__ nbr) {
    int idx = blockIdx.x * 256 + threadIdx.x;   // float4 index, total 4194304
    int n = idx >> 14;                          // image = b*64 + i
    int r = idx & 16383;
    int b = n >> 6;
    float4 s = ((const float4*)hx)[idx];
    #pragma unroll
    for (int k = 0; k < 4; ++k) {
        int j = nbr[n * 4 + k];
        if (j >= 0) {
            float4 v = ((const float4*)nset)[((b * 64 + j) << 14) + r];
            s.x += v.x; s.y += v.y; s.z += v.z; s.w += v.w;
        }
    }
    s.x = fmaxf(s.x, 0.f); s.y = fmaxf(s.y, 0.f);
    s.z = fmaxf(s.z, 0.f); s.w = fmaxf(s.w, 0.f);
    ((float4*)hx)[idx] = s;
}

// ---------------------------------------------------------------------------
// out = relu(h2 + sum_k nset[neighbor_k] + residual)   (in-place on h2)
// ---------------------------------------------------------------------------
__global__ __launch_bounds__(256) void final_kernel(float* __restrict__ h2,
                                                    const float* __restrict__ nset,
                                                    const int* __restrict__ nbr,
                                                    const float* __restrict__ resid) {
    int idx = blockIdx.x * 256 + threadIdx.x;
    int n = idx >> 14;
    int r = idx & 16383;
    int b = n >> 6;
    float4 s = ((const float4*)h2)[idx];
    float4 rx = ((const float4*)resid)[idx];
    s.x += rx.x; s.y += rx.y; s.z += rx.z; s.w += rx.w;
    #pragma unroll
    for (int k = 0; k < 4; ++k) {
        int j = nbr[n * 4 + k];
        if (j >= 0) {
            float4 v = ((const float4*)nset)[((b * 64 + j) << 14) + r];
            s.x += v.x; s.y += v.y; s.z += v.z; s.w += v.w;
        }
    }
    s.x = fmaxf(s.x, 0.f); s.y = fmaxf(s.y, 0.f);
    s.z = fmaxf(s.z, 0.f); s.w = fmaxf(s.w, 0.f);
    ((float4*)h2)[idx] = s;
}

// ---------------------------------------------------------------------------
extern "C" void kernel_launch(void* const* d_in, const int* in_sizes, int n_in,
                              void* d_out, int out_size, void* d_ws, size_t ws_size,
                              hipStream_t stream) {
    // setup_inputs order:
    // 0:x 1:w_x0 2:b_x0 3:w_n0 4:b_n0 5:w_x1 6:b_x1 7:w_n1 8:b_n1 9:mask 10:connected_num
    const float* x    = (const float*)d_in[0];
    const float* w_x0 = (const float*)d_in[1];
    const float* b_x0 = (const float*)d_in[2];
    const float* w_n0 = (const float*)d_in[3];
    const float* b_n0 = (const float*)d_in[4];
    const float* w_x1 = (const float*)d_in[5];
    const float* b_x1 = (const float*)d_in[6];
    const float* w_n1 = (const float*)d_in[7];
    const float* b_n1 = (const float*)d_in[8];
    const unsigned char* mask = (const unsigned char*)d_in[9];

    float* bufA = (float*)d_ws;                    // n_set     (64 MiB)
    float* bufB = bufA + (size_t)NIMG * IMGSZ;     // hx -> h   (64 MiB)
    int*   nbr  = (int*)(bufB + (size_t)NIMG * IMGSZ);
    float* outf = (float*)d_out;                   // h2x -> out (in-place finish)

    build_nbr_kernel<<<1, 256, 0, stream>>>(mask, nbr);

    // layer 0
    conv3x3_kernel<<<4096, 256, 0, stream>>>(x, w_n0, b_n0, bufA);   // n_set
    conv3x3_kernel<<<4096, 256, 0, stream>>>(x, w_x0, b_x0, bufB);   // hx
    agg_relu_kernel<<<16384, 256, 0, stream>>>(bufB, bufA, nbr);     // h = relu(hx+agg)

    // layer 1
    conv3x3_kernel<<<4096, 256, 0, stream>>>(bufB, w_n1, b_n1, bufA); // n_set
    conv3x3_kernel<<<4096, 256, 0, stream>>>(bufB, w_x1, b_x1, outf); // h2x
    final_kernel<<<16384, 256, 0, stream>>>(outf, bufA, nbr, x);      // out
}

// Round 4
// 398.456 us; speedup vs baseline: 6.4797x; 6.4797x over previous
//
#include <hip/hip_runtime.h>

// B=4, L=64, C=64, H=W=32, K=3, CONN=4
#define NIMG 256
#define CCH 64
#define HWSZ 1024
#define IMG_NHWC 65536            // 1024 px * 64 c (bf16 elements per image)

typedef __attribute__((ext_vector_type(8))) short  s16x8;
typedef __attribute__((ext_vector_type(4))) short  s16x4;
typedef __attribute__((ext_vector_type(4))) float  f32x4;

__device__ __forceinline__ unsigned short f2bf(float f) {
    unsigned u = __builtin_bit_cast(unsigned, f);
    u += 0x7fffu + ((u >> 16) & 1u);          // RNE
    return (unsigned short)(u >> 16);
}
__device__ __forceinline__ float bf2f(unsigned short h) {
    unsigned u = ((unsigned)h) << 16;
    return __builtin_bit_cast(float, u);
}

// ---------------------------------------------------------------------------
// nbr[n][4] from adjacency mask (byte-bool or int32, auto-detected). Validated R2.
// ---------------------------------------------------------------------------
__global__ __launch_bounds__(256) void build_nbr_kernel(const unsigned char* __restrict__ mraw,
                                                        int* __restrict__ nbr) {
    __shared__ int nz;
    int t = threadIdx.x;
    if (t == 0) nz = 0;
    __syncthreads();
    int local = 0;
    for (int i = t; i < 16384; i += 256) local += (mraw[i] != 0) ? 1 : 0;
    atomicAdd(&nz, local);
    __syncthreads();
    bool isByte = (nz == 1024);
    const int* mi = (const int*)mraw;
    int c = 0;
    int base = t * 64;
    for (int j = 0; j < 64; ++j) {
        int v = isByte ? (int)mraw[base + j] : mi[base + j];
        if (v != 0 && c < 4) { nbr[t * 4 + c] = j; ++c; }
    }
    for (; c < 4; ++c) nbr[t * 4 + c] = -1;
}

// ---------------------------------------------------------------------------
// Pack conv weights OIHW f32 -> [conv][tap][co][ci] bf16 (A-operand friendly).
// ---------------------------------------------------------------------------
__global__ __launch_bounds__(256) void pack_w_kernel(const float* __restrict__ w0,
                                                     const float* __restrict__ w1,
                                                     const float* __restrict__ w2,
                                                     const float* __restrict__ w3,
                                                     unsigned short* __restrict__ wp) {
    int idx = blockIdx.x * 256 + threadIdx.x;      // 4*9*64*64 = 147456
    if (idx >= 147456) return;
    int ci = idx & 63, co = (idx >> 6) & 63;
    int tc = idx >> 12;                            // conv*9 + tap
    int cv = tc / 9, tap = tc - cv * 9;
    const float* w = (cv == 0) ? w0 : (cv == 1) ? w1 : (cv == 2) ? w2 : w3;
    wp[idx] = f2bf(w[(co * 64 + ci) * 9 + tap]);
}

// ---------------------------------------------------------------------------
// NCHW f32 -> NHWC bf16, LDS-tiled transpose. Block = quarter image (256 px).
// LDS rows 68 bf16 (136B): phaseA b32 writes are 2-way (free); phaseB b64 aligned.
// ---------------------------------------------------------------------------
__global__ __launch_bounds__(256) void to_nhwc_kernel(const float* __restrict__ x,
                                                      unsigned short* __restrict__ xb) {
    __shared__ unsigned short lds[256 * 68];
    int bid = blockIdx.x;                 // 1024
    int n = bid >> 2, px0 = (bid & 3) * 256;
    int t = threadIdx.x, w = t >> 6, l = t & 63;

    #pragma unroll
    for (int pp = 0; pp < 8; ++pp) {      // channel pairs per wave
        int c = w * 16 + pp * 2;
        const float* s0 = x + ((size_t)(n * 64 + c)) * HWSZ + px0;
        const float* s1 = s0 + HWSZ;
        #pragma unroll
        for (int ch = 0; ch < 4; ++ch) {
            int px = ch * 64 + l;
            unsigned pack = (unsigned)f2bf(s0[px]) | ((unsigned)f2bf(s1[px]) << 16);
            *(unsigned*)((char*)lds + px * 136 + c * 2) = pack;
        }
    }
    __syncthreads();
    #pragma unroll
    for (int it = 0; it < 8; ++it) {
        int pos = it * 256 + t;
        int px = pos >> 3, c0 = (pos & 7) * 8;
        const char* src = (const char*)lds + px * 136 + c0 * 2;
        s16x4 v0 = *(const s16x4*)src;
        s16x4 v1 = *(const s16x4*)(src + 8);
        unsigned short* dst = xb + ((size_t)(n * 1024) + px0 + px) * 64 + c0;
        *(s16x4*)dst = v0;
        *(s16x4*)(dst + 4) = v1;
    }
}

// ---------------------------------------------------------------------------
// MFMA conv3x3 (pad 1) on NHWC bf16. Block = image x 8-row stripe x all 64 co.
// LDS: [10 rows][34 cols][64 ci] bf16, XOR-swizzled (^((col&7)<<4)) -> balanced
// banks for the stride-128B B-fragment reads. Zero halo staged, loop branch-free.
// Wave w: rows {2w, 2w+1}; acc[m][p]: m = co-tile(4), p = px-tile(2 rows x 2 halves).
// ---------------------------------------------------------------------------
__global__ __launch_bounds__(256, 2) void conv_mfma_kernel(const unsigned short* __restrict__ act,
                                                           const unsigned short* __restrict__ wp,
                                                           const float* __restrict__ bias,
                                                           unsigned short* __restrict__ outp) {
    __shared__ unsigned short lds[10 * 34 * 64];   // 43520 B
    int bid = blockIdx.x;                          // 1024
    int n = bid >> 2, stripe = bid & 3;
    int y0 = stripe * 8;
    int t = threadIdx.x, w = t >> 6, l = t & 63;

    // ---- stage input stripe (+halo) into swizzled LDS ----
    {
        const unsigned short* img = act + ((size_t)n << 16);
        int x1 = (t >> 3) & 31, slot = t & 7;
        int c = x1 + 1;
        int lbase = (c * 128 + slot * 16) ^ ((c & 7) << 4);
        #pragma unroll
        for (int r = 0; r < 10; ++r) {
            int y = y0 - 1 + r;
            s16x8 v = {0,0,0,0,0,0,0,0};
            if (y >= 0 && y < 32) v = *(const s16x8*)(img + (y * 32 + x1) * 64 + slot * 8);
            *(s16x8*)((char*)lds + r * 4352 + lbase) = v;
        }
        if (t < 160) {  // pad columns 0 and 33
            int r = t >> 4, cp = ((t >> 3) & 1) ? 33 : 0, sl = t & 7;
            s16x8 z = {0,0,0,0,0,0,0,0};
            int off = ((r * 34 + cp) * 128 + sl * 16) ^ ((cp & 7) << 4);
            *(s16x8*)((char*)lds + off) = z;
        }
    }
    __syncthreads();

    int lm = l & 15, kg = l >> 4;
    f32x4 acc[4][4];
    #pragma unroll
    for (int m = 0; m < 4; ++m)
        #pragma unroll
        for (int p = 0; p < 4; ++p) acc[m][p] = (f32x4){0.f, 0.f, 0.f, 0.f};

    const unsigned short* wlane = wp + lm * 64 + kg * 8;

    #pragma unroll
    for (int tap = 0; tap < 9; ++tap) {
        const int dy = tap / 3, dx = tap % 3;      // folds under unroll
        #pragma unroll
        for (int g = 0; g < 2; ++g) {
            s16x8 a[4], bfr[4];
            #pragma unroll
            for (int m = 0; m < 4; ++m)
                a[m] = *(const s16x8*)(wlane + (tap * 64 + m * 16) * 64 + g * 32);
            #pragma unroll
            for (int p = 0; p < 4; ++p) {
                int r  = 2 * w + (p >> 1) + dy;
                int xl = (p & 1) * 16 + lm + dx;
                int lb = (r * 4352 + xl * 128 + g * 64 + kg * 16) ^ ((xl & 7) << 4);
                bfr[p] = *(const s16x8*)((char*)lds + lb);
            }
            #pragma unroll
            for (int m = 0; m < 4; ++m)
                #pragma unroll
                for (int p = 0; p < 4; ++p)
                    acc[m][p] = __builtin_amdgcn_mfma_f32_16x16x32_bf16(a[m], bfr[p], acc[m][p], 0, 0, 0);
        }
    }

    // ---- bias + store NHWC bf16. D: col(px)=lane&15, row(co)=kg*4+reg (m89) ----
    #pragma unroll
    for (int m = 0; m < 4; ++m) {
        f32x4 bv = *(const f32x4*)(bias + m * 16 + kg * 4);
        #pragma unroll
        for (int p = 0; p < 4; ++p) {
            int y  = y0 + 2 * w + (p >> 1);
            int xx = (p & 1) * 16 + lm;
            s16x4 o;
            #pragma unroll
            for (int j = 0; j < 4; ++j) o[j] = (short)f2bf(acc[m][p][j] + bv[j]);
            *(s16x4*)(outp + (((size_t)n * 1024 + y * 32 + xx) * 64) + m * 16 + kg * 4) = o;
        }
    }
}

// ---------------------------------------------------------------------------
// h = relu(hx + sum_k nset[nbr_k])  in-place on NHWC bf16 (16B per thread).
// ---------------------------------------------------------------------------
__global__ __launch_bounds__(256) void agg_relu_kernel(unsigned short* __restrict__ hx,
                                                       const unsigned short* __restrict__ nset,
                                                       const int* __restrict__ nbr) {
    int bid = blockIdx.x;                          // 8192
    int n = bid >> 5;                              // uniform per block
    int b = n >> 6;
    int rem = ((bid & 31) << 8) + threadIdx.x;     // 16B unit within image
    size_t u = (((size_t)n) << 13) + rem;
    s16x8 hv = *(const s16x8*)(hx + u * 8);
    float s[8];
    #pragma unroll
    for (int j = 0; j < 8; ++j) s[j] = bf2f((unsigned short)hv[j]);
    #pragma unroll
    for (int k = 0; k < 4; ++k) {
        int jn = nbr[n * 4 + k];
        if (jn >= 0) {
            s16x8 nv = *(const s16x8*)(nset + ((((size_t)(b * 64 + jn)) << 13) + rem) * 8);
            #pragma unroll
            for (int j = 0; j < 8; ++j) s[j] += bf2f((unsigned short)nv[j]);
        }
    }
    s16x8 o;
    #pragma unroll
    for (int j = 0; j < 8; ++j) o[j] = (short)f2bf(fmaxf(s[j], 0.f));
    *(s16x8*)(hx + u * 8) = o;
}

// ---------------------------------------------------------------------------
// out = relu(h2x + sum_k nset[nbr_k] + x), NHWC bf16 -> NCHW f32 via LDS.
// Block = 128 px. LDS [128][68] f32: phaseA 2xb128 writes uniform; phase2 b128
// reads balanced (8 lanes per 4-bank group x 8 groups); all global IO coalesced.
// ---------------------------------------------------------------------------
__global__ __launch_bounds__(256) void final_kernel(const unsigned short* __restrict__ h2x,
                                                    const unsigned short* __restrict__ nset,
                                                    const int* __restrict__ nbr,
                                                    const float* __restrict__ x,
                                                    float* __restrict__ out) {
    __shared__ float lds[128 * 68];
    int bid = blockIdx.x;                          // 2048
    int n = bid >> 3, px0 = (bid & 7) * 128;
    int b = n >> 6;
    int t = threadIdx.x;
    int j0 = nbr[n * 4 + 0], j1 = nbr[n * 4 + 1], j2 = nbr[n * 4 + 2], j3 = nbr[n * 4 + 3];
    size_t base = ((size_t)n * 1024 + px0) * 64;
    size_t nb[4];
    nb[0] = ((size_t)(b * 64 + (j0 < 0 ? 0 : j0)) * 1024 + px0) * 64;
    nb[1] = ((size_t)(b * 64 + (j1 < 0 ? 0 : j1)) * 1024 + px0) * 64;
    nb[2] = ((size_t)(b * 64 + (j2 < 0 ? 0 : j2)) * 1024 + px0) * 64;
    nb[3] = ((size_t)(b * 64 + (j3 < 0 ? 0 : j3)) * 1024 + px0) * 64;
    int use[4] = {j0 >= 0, j1 >= 0, j2 >= 0, j3 >= 0};

    #pragma unroll
    for (int it = 0; it < 4; ++it) {
        int pos = it * 256 + t;
        int px = pos >> 3, c0 = (pos & 7) * 8;
        int off = px * 64 + c0;
        float s[8];
        s16x8 hv = *(const s16x8*)(h2x + base + off);
        #pragma unroll
        for (int j = 0; j < 8; ++j) s[j] = bf2f((unsigned short)hv[j]);
        #pragma unroll
        for (int k = 0; k < 4; ++k) {
            if (use[k]) {
                s16x8 nv = *(const s16x8*)(nset + nb[k] + off);
                #pragma unroll
                for (int j = 0; j < 8; ++j) s[j] += bf2f((unsigned short)nv[j]);
            }
        }
        float* dst = &lds[px * 68 + c0];
        *(f32x4*)dst = (f32x4){s[0], s[1], s[2], s[3]};
        *(f32x4*)(dst + 4) = (f32x4){s[4], s[5], s[6], s[7]};
    }
    __syncthreads();

    int w = t >> 6, l = t & 63;
    #pragma unroll
    for (int q = 0; q < 4; ++q) {
        int c0 = w * 16 + q * 4;
        #pragma unroll
        for (int half = 0; half < 2; ++half) {
            int px = half * 64 + l;
            f32x4 v = *(const f32x4*)&lds[px * 68 + c0];
            #pragma unroll
            for (int j = 0; j < 4; ++j) {
                size_t a = ((size_t)(n * 64) + c0 + j) * HWSZ + px0 + px;
                out[a] = fmaxf(v[j] + x[a], 0.f);
            }
        }
    }
}

// ---------------------------------------------------------------------------
extern "C" void kernel_launch(void* const* d_in, const int* in_sizes, int n_in,
                              void* d_out, int out_size, void* d_ws, size_t ws_size,
                              hipStream_t stream) {
    const float* x    = (const float*)d_in[0];
    const float* w_x0 = (const float*)d_in[1];
    const float* b_x0 = (const float*)d_in[2];
    const float* w_n0 = (const float*)d_in[3];
    const float* b_n0 = (const float*)d_in[4];
    const float* w_x1 = (const float*)d_in[5];
    const float* b_x1 = (const float*)d_in[6];
    const float* w_n1 = (const float*)d_in[7];
    const float* b_n1 = (const float*)d_in[8];
    const unsigned char* mask = (const unsigned char*)d_in[9];

    unsigned short* xb    = (unsigned short*)d_ws;              // x NHWC bf16 -> later h2x
    unsigned short* hxb   = xb  + (size_t)NIMG * IMG_NHWC;      // hx -> h (in-place agg)
    unsigned short* nsetb = hxb + (size_t)NIMG * IMG_NHWC;      // n_set
    unsigned short* wpack = nsetb + (size_t)NIMG * IMG_NHWC;    // [4][9][64][64]
    int* nbr = (int*)(wpack + 147456);

    build_nbr_kernel<<<1, 256, 0, stream>>>(mask, nbr);
    pack_w_kernel<<<576, 256, 0, stream>>>(w_n0, w_x0, w_n1, w_x1, wpack);
    to_nhwc_kernel<<<1024, 256, 0, stream>>>(x, xb);

    const unsigned short* wp_n0 = wpack;
    const unsigned short* wp_x0 = wpack + 36864;
    const unsigned short* wp_n1 = wpack + 73728;
    const unsigned short* wp_x1 = wpack + 110592;

    // layer 0
    conv_mfma_kernel<<<1024, 256, 0, stream>>>(xb, wp_n0, b_n0, nsetb);
    conv_mfma_kernel<<<1024, 256, 0, stream>>>(xb, wp_x0, b_x0, hxb);
    agg_relu_kernel<<<8192, 256, 0, stream>>>(hxb, nsetb, nbr);     // hxb -> h

    // layer 1 (h2x overwrites xb: x itself no longer needed in bf16 form)
    conv_mfma_kernel<<<1024, 256, 0, stream>>>(hxb, wp_n1, b_n1, nsetb);
    conv_mfma_kernel<<<1024, 256, 0, stream>>>(hxb, wp_x1, b_x1, xb);
    final_kernel<<<2048, 256, 0, stream>>>(xb, nsetb, nbr, x, (float*)d_out);
}